// Round 1
// baseline (929.649 us; speedup 1.0000x reference)
//
#include <hip/hip_runtime.h>
#include <stdint.h>
#include <stddef.h>

// ---------------------------------------------------------------------------
// Gemma2AttentionWithExpert: fused two-stream QKV + RoPE + GQA attention +
// per-stream output projection.  All GEMMs via f16 MFMA (16x16x32), fp32 acc.
// B=4, L1=1024, L2=512, L=1536, D_PG=2304, D_EX=1024, H=8, HKV=4, DH=256.
// ---------------------------------------------------------------------------

typedef _Float16 f16;
typedef _Float16 f16x8 __attribute__((ext_vector_type(8)));
typedef _Float16 f16x4 __attribute__((ext_vector_type(4)));
typedef float    f32x4 __attribute__((ext_vector_type(4)));

__device__ __forceinline__ void async_ld16(const void* g, void* l) {
  // 16B per lane, LDS dest = wave-uniform base + lane*16
  __builtin_amdgcn_global_load_lds((const __attribute__((address_space(1))) void*)g,
                                   (__attribute__((address_space(3))) void*)l,
                                   16, 0, 0);
}

// ---- 128x128 tile GEMM core, A:[M,K] row-major (lda), B:[N,K] row-major
// (ldb) i.e. B^T layout, K % 32 == 0.  256 threads = 4 waves as 2x2 of 64x64.
template <typename Epi>
__device__ __forceinline__ void gemm_core(const f16* __restrict__ A, int lda,
                                          const f16* __restrict__ Bm, int ldb,
                                          int K, Epi&& epi)
{
  __shared__ alignas(16) f16 At[128 * 32];
  __shared__ alignas(16) f16 Bt[128 * 32];

  const int t    = threadIdx.x;
  const int w    = t >> 6;
  const int lane = t & 63;
  const int q4   = lane >> 4;
  const int l16  = lane & 15;
  const int wm   = w >> 1;
  const int wn   = w & 1;

  const f32x4 vzero = {0.f, 0.f, 0.f, 0.f};
  f32x4 acc[4][4];
#pragma unroll
  for (int i = 0; i < 4; ++i)
#pragma unroll
    for (int j = 0; j < 4; ++j) acc[i][j] = vzero;

  // staging: thread t loads 8 f16 at (row = c*64 + t/4, col = (t&3)*8)
  const int srow = t >> 2;
  const int scol = (t & 3) << 3;
  const f16* aP = A  + (size_t)srow * lda + scol;
  const f16* bP = Bm + (size_t)srow * ldb + scol;
  f16* ldsA0 = At + w * 512;
  f16* ldsA1 = At + 2048 + w * 512;
  f16* ldsB0 = Bt + w * 512;
  f16* ldsB1 = Bt + 2048 + w * 512;
  const size_t a64 = (size_t)64 * lda;
  const size_t b64 = (size_t)64 * ldb;

  for (int k0 = 0; k0 < K; k0 += 32) {
    async_ld16(aP + k0,        ldsA0);
    async_ld16(aP + a64 + k0,  ldsA1);
    async_ld16(bP + k0,        ldsB0);
    async_ld16(bP + b64 + k0,  ldsB1);
    __syncthreads();   // drains vmcnt before barrier (compiler-enforced)

    f16x8 af[4], bf[4];
#pragma unroll
    for (int mi = 0; mi < 4; ++mi)
      af[mi] = *(const f16x8*)(At + (wm * 64 + mi * 16 + l16) * 32 + q4 * 8);
#pragma unroll
    for (int ni = 0; ni < 4; ++ni)
      bf[ni] = *(const f16x8*)(Bt + (wn * 64 + ni * 16 + l16) * 32 + q4 * 8);

#pragma unroll
    for (int mi = 0; mi < 4; ++mi)
#pragma unroll
      for (int ni = 0; ni < 4; ++ni)
        acc[mi][ni] = __builtin_amdgcn_mfma_f32_16x16x32_f16(af[mi], bf[ni], acc[mi][ni], 0, 0, 0);
    __syncthreads();
  }

  // C/D layout (m89-verified): row = quad*4 + reg, col = lane&15
#pragma unroll
  for (int mi = 0; mi < 4; ++mi)
#pragma unroll
    for (int ni = 0; ni < 4; ++ni)
#pragma unroll
      for (int r = 0; r < 4; ++r)
        epi(wm * 64 + mi * 16 + q4 * 4 + r, wn * 64 + ni * 16 + l16, acc[mi][ni][r]);
}

// ---- GEMM wrappers ---------------------------------------------------------
// Row remap for batch interleave: orow = (m>>rshift)*rstride + roff + (m&rmask)

__global__ __launch_bounds__(256) void k_gemm_f32(
    const f16* __restrict__ A, const f16* __restrict__ Bm, float* __restrict__ C,
    int lda, int ldb, int ldc, int K, int rshift, int rmask, int rstride, int roff)
{
  const f16* Ab = A  + (size_t)blockIdx.y * 128 * lda;
  const f16* Bb = Bm + (size_t)blockIdx.x * 128 * ldb;
  const int rowbase = blockIdx.y * 128, colbase = blockIdx.x * 128;
  gemm_core(Ab, lda, Bb, ldb, K, [&](int r, int c, float v) {
    int m = rowbase + r;
    int orow = (m >> rshift) * rstride + roff + (m & rmask);
    C[(size_t)orow * ldc + colbase + c] = v;
  });
}

__global__ __launch_bounds__(256) void k_gemm_f16(
    const f16* __restrict__ A, const f16* __restrict__ Bm, f16* __restrict__ C,
    int lda, int ldb, int ldc, int K, int rshift, int rmask, int rstride, int roff)
{
  const f16* Ab = A  + (size_t)blockIdx.y * 128 * lda;
  const f16* Bb = Bm + (size_t)blockIdx.x * 128 * ldb;
  const int rowbase = blockIdx.y * 128, colbase = blockIdx.x * 128;
  gemm_core(Ab, lda, Bb, ldb, K, [&](int r, int c, float v) {
    int m = rowbase + r;
    int orow = (m >> rshift) * rstride + roff + (m & rmask);
    C[(size_t)orow * ldc + colbase + c] = (f16)v;
  });
}

// scores chunk for one batch b: blockIdx.z = h (0..7); S = per-batch buffer
__global__ __launch_bounds__(256) void k_gemm_scores(
    const f16* __restrict__ qb, const f16* __restrict__ kb,
    const float* __restrict__ mask, float* __restrict__ S, int b)
{
  const int h = blockIdx.z;
  const int g = h >> 1;
  const f16* A  = qb + (size_t)b * 1536 * 2048 + h * 256 + (size_t)blockIdx.y * 128 * 2048;
  const f16* Bm = kb + (size_t)b * 1536 * 1024 + g * 256 + (size_t)blockIdx.x * 128 * 1024;
  float* Sz = S + (size_t)h * 1536 * 1536;
  const float* mb = mask + (size_t)b * 1536 * 1536;
  const int rowbase = blockIdx.y * 128, colbase = blockIdx.x * 128;
  gemm_core(A, 2048, Bm, 1024, 256, [&](int r, int c, float v) {
    size_t i = (size_t)(rowbase + r) * 1536 + (colbase + c);
    Sz[i] = v * 0.0625f + mb[i];
  });
}

// PV chunk for one batch b: P is f16 over the S buffer, row stride 3072 elems
__global__ __launch_bounds__(256) void k_gemm_pv(
    const f16* __restrict__ P, const f16* __restrict__ vt,
    f16* __restrict__ att0, f16* __restrict__ att1, int b)
{
  const int h = blockIdx.z, g = h >> 1;
  const f16* A  = P  + (size_t)h * 4718592 + (size_t)blockIdx.y * 128 * 3072;
  const f16* Bm = vt + (size_t)(b * 4 + g) * 256 * 1536 + (size_t)blockIdx.x * 128 * 1536;
  const int rowbase = blockIdx.y * 128, colbase = blockIdx.x * 128;
  gemm_core(A, 3072, Bm, 1536, 1536, [&](int r, int c, float v) {
    int m = rowbase + r;
    if (m < 1024) att0[(size_t)(b * 1024 + m)       * 2048 + h * 256 + colbase + c] = (f16)v;
    else          att1[(size_t)(b * 512 + m - 1024) * 2048 + h * 256 + colbase + c] = (f16)v;
  });
}

// ---- cast all fp32 inputs to f16, contiguous into ws -----------------------
__global__ __launch_bounds__(256) void k_cast_all(
    const float* __restrict__ s0, const float* __restrict__ s1,
    const float* __restrict__ s2, const float* __restrict__ s3,
    const float* __restrict__ s4, const float* __restrict__ s5,
    const float* __restrict__ s6, const float* __restrict__ s7,
    const float* __restrict__ s8, const float* __restrict__ s9,
    f16* __restrict__ dst)
{
  const size_t gid = ((size_t)blockIdx.x * 256 + threadIdx.x) * 4;
  const float* s; size_t off;
  if      (gid < 9437184ull)  { s = s0; off = gid;               }
  else if (gid < 11534336ull) { s = s1; off = gid - 9437184ull;  }
  else if (gid < 16252928ull) { s = s2; off = gid - 11534336ull; }
  else if (gid < 18612224ull) { s = s3; off = gid - 16252928ull; }
  else if (gid < 20971520ull) { s = s4; off = gid - 18612224ull; }
  else if (gid < 25690112ull) { s = s5; off = gid - 20971520ull; }
  else if (gid < 27787264ull) { s = s6; off = gid - 25690112ull; }
  else if (gid < 28835840ull) { s = s7; off = gid - 27787264ull; }
  else if (gid < 29884416ull) { s = s8; off = gid - 28835840ull; }
  else                        { s = s9; off = gid - 29884416ull; }
  float4 v = *(const float4*)(s + off);
  f16x4 o = {(f16)v.x, (f16)v.y, (f16)v.z, (f16)v.w};
  *(f16x4*)(dst + gid) = o;
}

// ---- RoPE (fp32 in, f16 out).  src layout [B*L, nh, 256], cos/sin [B*L,128]
__global__ __launch_bounds__(256) void k_rope(
    const float* __restrict__ src, f16* __restrict__ dst,
    const float* __restrict__ cs, const float* __restrict__ sn, int nhl2)
{
  int tid = blockIdx.x * 256 + threadIdx.x;
  int j  = tid & 127;
  int h  = (tid >> 7) & ((1 << nhl2) - 1);
  int bl = tid >> (7 + nhl2);
  size_t base = ((size_t)bl << (8 + nhl2)) + ((size_t)h << 8);
  float x1 = src[base + j];
  float x2 = src[base + 128 + j];
  float c = cs[(size_t)bl * 128 + j];
  float s = sn[(size_t)bl * 128 + j];
  dst[base + j]       = (f16)(x1 * c - x2 * s);
  dst[base + 128 + j] = (f16)(x2 * c + x1 * s);
}

// ---- V transpose: v[B*1536, 1024] -> vt[B][4][256][1536] -------------------
__global__ __launch_bounds__(256) void k_vtrans(const f16* __restrict__ v,
                                                f16* __restrict__ vt)
{
  __shared__ f16 tile[32][33];
  const int b = blockIdx.z;
  const int d0 = blockIdx.x * 32, l0 = blockIdx.y * 32;
  const int t = threadIdx.x;
  const int tr = t >> 5, tc = t & 31;
#pragma unroll
  for (int i = 0; i < 4; ++i) {
    int l = l0 + tr + i * 8;
    tile[tr + i * 8][tc] = v[((size_t)b * 1536 + l) * 1024 + d0 + tc];
  }
  __syncthreads();
#pragma unroll
  for (int i = 0; i < 4; ++i) {
    int d = d0 + tr + i * 8;
    int g = d >> 8, dw = d & 255;
    vt[(((size_t)b * 4 + g) * 256 + dw) * 1536 + l0 + tc] = tile[tc][tr + i * 8];
  }
}

// ---- row softmax over 1536, in place: fp32 row -> f16 P in first half ------
__global__ __launch_bounds__(256) void k_softmax(float* __restrict__ S)
{
  float* row = S + (size_t)blockIdx.x * 1536;
  f16* out = (f16*)row;
  const int t = threadIdx.x;
  const int w = t >> 6, lane = t & 63;
  __shared__ float red[8];

  float x[6];
  float mx = -3.0e38f;
#pragma unroll
  for (int i = 0; i < 6; ++i) { x[i] = row[t + i * 256]; mx = fmaxf(mx, x[i]); }
#pragma unroll
  for (int o = 32; o > 0; o >>= 1) mx = fmaxf(mx, __shfl_xor(mx, o, 64));
  if (lane == 0) red[w] = mx;
  __syncthreads();
  mx = fmaxf(fmaxf(red[0], red[1]), fmaxf(red[2], red[3]));

  float s = 0.f;
#pragma unroll
  for (int i = 0; i < 6; ++i) { x[i] = __expf(x[i] - mx); s += x[i]; }
#pragma unroll
  for (int o = 32; o > 0; o >>= 1) s += __shfl_xor(s, o, 64);
  __syncthreads();
  if (lane == 0) red[4 + w] = s;
  __syncthreads();   // also guarantees every thread's reads precede writes below
  float inv = 1.f / (red[4] + red[5] + red[6] + red[7]);
#pragma unroll
  for (int i = 0; i < 6; ++i) out[t + i * 256] = (f16)(x[i] * inv);
}

// ---------------------------------------------------------------------------
extern "C" void kernel_launch(void* const* d_in, const int* in_sizes, int n_in,
                              void* d_out, int out_size, void* d_ws, size_t ws_size,
                              hipStream_t stream)
{
  (void)in_sizes; (void)n_in; (void)out_size; (void)ws_size;
  const float* pg  = (const float*)d_in[0];
  const float* ex  = (const float*)d_in[1];
  const float* cs  = (const float*)d_in[2];
  const float* sn  = (const float*)d_in[3];
  const float* msk = (const float*)d_in[4];
  const float* wq0 = (const float*)d_in[5];
  const float* wk0 = (const float*)d_in[6];
  const float* wv0 = (const float*)d_in[7];
  const float* wo0 = (const float*)d_in[8];
  const float* wq1 = (const float*)d_in[9];
  const float* wk1 = (const float*)d_in[10];
  const float* wv1 = (const float*)d_in[11];
  const float* wo1 = (const float*)d_in[12];

  char* ws = (char*)d_ws;
  // f16 casts, contiguous from 0 in k_cast_all region order:
  f16* xpg  = (f16*)(ws + 0);           // [4096,2304]
  f16* xex  = (f16*)(ws + 18874368);    // [2048,1024]
  f16* wq0c = (f16*)(ws + 23068672);    // [2048,2304]
  f16* wk0c = (f16*)(ws + 32505856);    // [1024,2304]
  f16* wv0c = (f16*)(ws + 37224448);    // [1024,2304]
  f16* wo0c = (f16*)(ws + 41943040);    // [2304,2048]
  f16* wq1c = (f16*)(ws + 51380224);    // [2048,1024]
  f16* wk1c = (f16*)(ws + 55574528);    // [1024,1024]
  f16* wv1c = (f16*)(ws + 57671680);    // [1024,1024]
  f16* wo1c = (f16*)(ws + 59768832);    // [1024,2048]
  f16* qb   = (f16*)(ws + 63963136);    // [B*1536, 2048] roped f16
  f16* kb   = (f16*)(ws + 89128960);    // [B*1536, 1024]
  f16* vb   = (f16*)(ws + 101711872);   // [B*1536, 1024]
  f16* vt   = (f16*)(ws + 114294784);   // [B,4,256,1536]
  f16* att0 = (f16*)(ws + 126877696);   // [B*1024, 2048]
  f16* att1 = (f16*)(ws + 143654912);   // [B*512, 2048]
  float* Sf   = (float*)(ws + 152043520); // per-batch S chunk: 8*1536*1536 fp32
  float* qf32 = (float*)(ws + 152043520); // alias (dead before Sf written)
  float* kf32 = (float*)(ws + 202375168); // alias
  float* out0 = (float*)d_out;            // [4,1024,2304]
  float* out1 = out0 + 9437184;           // [4,512,1024]

  // 1) cast all fp32 inputs to f16
  k_cast_all<<<31232, 256, 0, stream>>>(pg, ex, wq0, wk0, wv0, wo0, wq1, wk1, wv1, wo1, (f16*)ws);

  // 2) QKV projections (pg rows -> b*1536 + l, ex rows -> b*1536 + 1024 + l)
  k_gemm_f32<<<dim3(16, 32), 256, 0, stream>>>(xpg, wq0c, qf32, 2304, 2304, 2048, 2304, 10, 1023, 1536, 0);
  k_gemm_f32<<<dim3(8, 32),  256, 0, stream>>>(xpg, wk0c, kf32, 2304, 2304, 1024, 2304, 10, 1023, 1536, 0);
  k_gemm_f16<<<dim3(8, 32),  256, 0, stream>>>(xpg, wv0c, vb,   2304, 2304, 1024, 2304, 10, 1023, 1536, 0);
  k_gemm_f32<<<dim3(16, 16), 256, 0, stream>>>(xex, wq1c, qf32, 1024, 1024, 2048, 1024, 9, 511, 1536, 1024);
  k_gemm_f32<<<dim3(8, 16),  256, 0, stream>>>(xex, wk1c, kf32, 1024, 1024, 1024, 1024, 9, 511, 1536, 1024);
  k_gemm_f16<<<dim3(8, 16),  256, 0, stream>>>(xex, wv1c, vb,   1024, 1024, 1024, 1024, 9, 511, 1536, 1024);

  // 3) RoPE q (nh=8) and k (nh=4); fp32 math, f16 out
  k_rope<<<24576, 256, 0, stream>>>(qf32, qb, cs, sn, 3);
  k_rope<<<12288, 256, 0, stream>>>(kf32, kb, cs, sn, 2);

  // 4) V transpose for PV B^T layout
  k_vtrans<<<dim3(32, 48, 4), 256, 0, stream>>>(vb, vt);

  // 5) attention, chunked per batch (S chunk reuses qf32/kf32 space)
  for (int b = 0; b < 4; ++b) {
    k_gemm_scores<<<dim3(12, 12, 8), 256, 0, stream>>>(qb, kb, msk, Sf, b);
    k_softmax<<<12288, 256, 0, stream>>>(Sf);
    k_gemm_pv<<<dim3(2, 12, 8), 256, 0, stream>>>((const f16*)Sf, vt, att0, att1, b);
  }

  // 6) output projections
  k_gemm_f32<<<dim3(18, 32), 256, 0, stream>>>(att0, wo0c, out0, 2048, 2048, 2304, 2048, 30, (1 << 30) - 1, 0, 0);
  k_gemm_f32<<<dim3(8, 16),  256, 0, stream>>>(att1, wo1c, out1, 2048, 2048, 1024, 2048, 30, (1 << 30) - 1, 0, 0);
}

// Round 2
// 701.978 us; speedup vs baseline: 1.3243x; 1.3243x over previous
//
#include <hip/hip_runtime.h>
#include <stdint.h>
#include <stddef.h>

// ---------------------------------------------------------------------------
// Gemma2AttentionWithExpert: fused two-stream QKV + RoPE + GQA attention +
// per-stream output projection.  All GEMMs via f16 MFMA (16x16x32), fp32 acc.
// B=4, L1=1024, L2=512, L=1536, D_PG=2304, D_EX=1024, H=8, HKV=4, DH=256.
// Round 2: merged QKV (1536-block launch), merged O-proj, f16 S with
// double-buffered chunks, pv_b fused into scores_{b+1} launch, wave softmax.
// ---------------------------------------------------------------------------

typedef _Float16 f16;
typedef _Float16 f16x8 __attribute__((ext_vector_type(8)));
typedef _Float16 f16x4 __attribute__((ext_vector_type(4)));
typedef float    f32x4 __attribute__((ext_vector_type(4)));

__device__ __forceinline__ void async_ld16(const void* g, void* l) {
  // 16B per lane, LDS dest = wave-uniform base + lane*16
  __builtin_amdgcn_global_load_lds((const __attribute__((address_space(1))) void*)g,
                                   (__attribute__((address_space(3))) void*)l,
                                   16, 0, 0);
}

// ---- 128x128 tile GEMM core, A:[M,K] row-major (lda), B:[N,K] row-major
// (ldb) i.e. B^T layout, K % 32 == 0.  256 threads = 4 waves as 2x2 of 64x64.
// LDS (2 x 128*32 f16 = 16 KiB) is passed in so multi-path kernels share it.
template <typename Epi>
__device__ __forceinline__ void gemm_core(f16* At, f16* Bt,
                                          const f16* __restrict__ A, int lda,
                                          const f16* __restrict__ Bm, int ldb,
                                          int K, Epi&& epi)
{
  const int t    = threadIdx.x;
  const int w    = t >> 6;
  const int lane = t & 63;
  const int q4   = lane >> 4;
  const int l16  = lane & 15;
  const int wm   = w >> 1;
  const int wn   = w & 1;

  const f32x4 vzero = {0.f, 0.f, 0.f, 0.f};
  f32x4 acc[4][4];
#pragma unroll
  for (int i = 0; i < 4; ++i)
#pragma unroll
    for (int j = 0; j < 4; ++j) acc[i][j] = vzero;

  // staging: thread t loads 8 f16 at (row = c*64 + t/4, col = (t&3)*8)
  const int srow = t >> 2;
  const int scol = (t & 3) << 3;
  const f16* aP = A  + (size_t)srow * lda + scol;
  const f16* bP = Bm + (size_t)srow * ldb + scol;
  f16* ldsA0 = At + w * 512;
  f16* ldsA1 = At + 2048 + w * 512;
  f16* ldsB0 = Bt + w * 512;
  f16* ldsB1 = Bt + 2048 + w * 512;
  const size_t a64 = (size_t)64 * lda;
  const size_t b64 = (size_t)64 * ldb;

  for (int k0 = 0; k0 < K; k0 += 32) {
    async_ld16(aP + k0,        ldsA0);
    async_ld16(aP + a64 + k0,  ldsA1);
    async_ld16(bP + k0,        ldsB0);
    async_ld16(bP + b64 + k0,  ldsB1);
    __syncthreads();

    f16x8 af[4], bf[4];
#pragma unroll
    for (int mi = 0; mi < 4; ++mi)
      af[mi] = *(const f16x8*)(At + (wm * 64 + mi * 16 + l16) * 32 + q4 * 8);
#pragma unroll
    for (int ni = 0; ni < 4; ++ni)
      bf[ni] = *(const f16x8*)(Bt + (wn * 64 + ni * 16 + l16) * 32 + q4 * 8);

#pragma unroll
    for (int mi = 0; mi < 4; ++mi)
#pragma unroll
      for (int ni = 0; ni < 4; ++ni)
        acc[mi][ni] = __builtin_amdgcn_mfma_f32_16x16x32_f16(af[mi], bf[ni], acc[mi][ni], 0, 0, 0);
    __syncthreads();
  }

  // C/D layout (m89-verified): row = quad*4 + reg, col = lane&15
#pragma unroll
  for (int mi = 0; mi < 4; ++mi)
#pragma unroll
    for (int ni = 0; ni < 4; ++ni)
#pragma unroll
      for (int r = 0; r < 4; ++r)
        epi(wm * 64 + mi * 16 + q4 * 4 + r, wn * 64 + ni * 16 + l16, acc[mi][ni][r]);
}

// ---- fused QKV: both streams, q/k/v written f16 (q/k roped later in place)
// blocks [0,1024): stream0 (xpg @ W0cat, K=2304, M=4096, N=4096)
// blocks [1024,1536): stream1 (xex @ W1cat, K=1024, M=2048, N=4096)
__global__ __launch_bounds__(256) void k_qkv(
    const f16* __restrict__ xpg, const f16* __restrict__ xex,
    const f16* __restrict__ W0,  const f16* __restrict__ W1,
    f16* __restrict__ q, f16* __restrict__ k, f16* __restrict__ v)
{
  __shared__ alignas(16) f16 At[128 * 32];
  __shared__ alignas(16) f16 Bt[128 * 32];
  const int idx = blockIdx.x;
  const bool s0 = idx < 1024;
  int by, bx, K;
  const f16 *A, *B;
  if (s0) { by = idx >> 5; bx = idx & 31; K = 2304;
            A = xpg + (size_t)by * 128 * 2304; B = W0 + (size_t)bx * 128 * 2304; }
  else    { int j = idx - 1024; by = j >> 5; bx = j & 31; K = 1024;
            A = xex + (size_t)by * 128 * 1024; B = W1 + (size_t)bx * 128 * 1024; }
  const int rowbase = by * 128, colbase = bx * 128;
  gemm_core(At, Bt, A, K, B, K, K, [&](int r, int c, float fv) {
    int m = rowbase + r;
    int row = s0 ? ((m >> 10) * 1536 + (m & 1023))
                 : ((m >> 9) * 1536 + 1024 + (m & 511));
    int col = colbase + c;
    f16 h = (f16)fv;
    if      (col < 2048) q[(size_t)row * 2048 + col]        = h;
    else if (col < 3072) k[(size_t)row * 1024 + col - 2048] = h;
    else                 v[(size_t)row * 1024 + col - 3072] = h;
  });
}

// ---- in-place RoPE on f16 q (8 heads) and k (4 heads), fp32 math ----------
__global__ __launch_bounds__(256) void k_rope2(
    f16* __restrict__ q, f16* __restrict__ k,
    const float* __restrict__ cs, const float* __restrict__ sn)
{
  const int tid = blockIdx.x * 256 + threadIdx.x;
  f16* base; int j, bl;
  if (tid < 6291456) {           // q: 6144 rows * 8 heads * 128 pairs
    j = tid & 127; int h = (tid >> 7) & 7; bl = tid >> 10;
    base = q + ((size_t)bl << 11) + (h << 8);
  } else {                       // k: 6144 rows * 4 heads * 128 pairs
    int t2 = tid - 6291456;
    j = t2 & 127; int h = (t2 >> 7) & 3; bl = t2 >> 9;
    base = k + ((size_t)bl << 10) + (h << 8);
  }
  float x1 = (float)base[j], x2 = (float)base[128 + j];
  float c = cs[(size_t)bl * 128 + j], s = sn[(size_t)bl * 128 + j];
  base[j]       = (f16)(x1 * c - x2 * s);
  base[128 + j] = (f16)(x2 * c + x1 * s);
}

// ---- V transpose: v[B*1536, 1024] -> vt[B][4][256][1536] -------------------
__global__ __launch_bounds__(256) void k_vtrans(const f16* __restrict__ v,
                                                f16* __restrict__ vt)
{
  __shared__ f16 tile[32][33];
  const int b = blockIdx.z;
  const int d0 = blockIdx.x * 32, l0 = blockIdx.y * 32;
  const int t = threadIdx.x;
  const int tr = t >> 5, tc = t & 31;
#pragma unroll
  for (int i = 0; i < 4; ++i) {
    int l = l0 + tr + i * 8;
    tile[tr + i * 8][tc] = v[((size_t)b * 1536 + l) * 1024 + d0 + tc];
  }
  __syncthreads();
#pragma unroll
  for (int i = 0; i < 4; ++i) {
    int d = d0 + tr + i * 8;
    int g = d >> 8, dw = d & 255;
    vt[(((size_t)b * 4 + g) * 256 + dw) * 1536 + l0 + tc] = tile[tc][tr + i * 8];
  }
}

// ---- attention mega-kernel: blocks [0,npv) do PV for batch b_pv reading
// Psrc; blocks [npv, npv+1152) do scores for batch b_sc writing f16 Sdst.
__global__ __launch_bounds__(256) void k_attn(
    const f16* __restrict__ qb, const f16* __restrict__ kb,
    const float* __restrict__ mask, f16* __restrict__ Sdst,
    const f16* __restrict__ Psrc, const f16* __restrict__ vt,
    f16* __restrict__ att0, f16* __restrict__ att1,
    int b_sc, int b_pv, int npv)
{
  __shared__ alignas(16) f16 At[128 * 32];
  __shared__ alignas(16) f16 Bt[128 * 32];
  const int idx = blockIdx.x;
  if (idx < npv) {
    // PV: O[q, dh] = P[q,k] @ V^T[dh,k]^T ; M=1536, N=256/head, K=1536
    const int h = idx / 24, rem = idx % 24, by = rem >> 1, bx = rem & 1;
    const f16* A = Psrc + (size_t)h * 1536 * 1536 + (size_t)by * 128 * 1536;
    const f16* B = vt + (size_t)(b_pv * 4 + (h >> 1)) * 256 * 1536 + (size_t)bx * 128 * 1536;
    const int rowbase = by * 128, colbase = bx * 128;
    gemm_core(At, Bt, A, 1536, B, 1536, 1536, [&](int r, int c, float fv) {
      int m = rowbase + r;
      if (m < 1024) att0[((size_t)(b_pv * 1024 + m))       * 2048 + h * 256 + colbase + c] = (f16)fv;
      else          att1[((size_t)(b_pv * 512 + m - 1024)) * 2048 + h * 256 + colbase + c] = (f16)fv;
    });
  } else {
    // scores: S[q,kpos] = (q . k) * 1/16 + mask, f16 out; K=256
    const int j = idx - npv;
    const int h = j / 144, rem = j % 144, by = rem / 12, bx = rem % 12;
    const f16* A = qb + (size_t)b_sc * 1536 * 2048 + h * 256 + (size_t)by * 128 * 2048;
    const f16* B = kb + (size_t)b_sc * 1536 * 1024 + (h >> 1) * 256 + (size_t)bx * 128 * 1024;
    f16* Sz = Sdst + (size_t)h * 1536 * 1536;
    const float* mb = mask + (size_t)b_sc * 1536 * 1536;
    const int rowbase = by * 128, colbase = bx * 128;
    gemm_core(At, Bt, A, 2048, B, 1024, 256, [&](int r, int c, float fv) {
      size_t i = (size_t)(rowbase + r) * 1536 + colbase + c;
      Sz[i] = (f16)(fv * 0.0625f + mb[i]);
    });
  }
}

// ---- wave-per-row softmax over 1536, f16 in/out, in place ------------------
__global__ __launch_bounds__(256) void k_softmax(f16* __restrict__ S)
{
  const int row = blockIdx.x * 4 + (threadIdx.x >> 6);
  const int lane = threadIdx.x & 63;
  f16* p = S + (size_t)row * 1536 + lane * 8;
  f16x8 v0 = *(const f16x8*)p;
  f16x8 v1 = *(const f16x8*)(p + 512);
  f16x8 v2 = *(const f16x8*)(p + 1024);
  float x[24];
#pragma unroll
  for (int i = 0; i < 8; ++i) {
    x[i] = (float)v0[i]; x[8 + i] = (float)v1[i]; x[16 + i] = (float)v2[i];
  }
  float mx = x[0];
#pragma unroll
  for (int i = 1; i < 24; ++i) mx = fmaxf(mx, x[i]);
#pragma unroll
  for (int o = 32; o > 0; o >>= 1) mx = fmaxf(mx, __shfl_xor(mx, o, 64));
  float s = 0.f;
#pragma unroll
  for (int i = 0; i < 24; ++i) { x[i] = __expf(x[i] - mx); s += x[i]; }
#pragma unroll
  for (int o = 32; o > 0; o >>= 1) s += __shfl_xor(s, o, 64);
  const float inv = 1.f / s;
  f16x8 o0, o1, o2;
#pragma unroll
  for (int i = 0; i < 8; ++i) {
    o0[i] = (f16)(x[i] * inv); o1[i] = (f16)(x[8 + i] * inv); o2[i] = (f16)(x[16 + i] * inv);
  }
  *(f16x8*)p = o0; *(f16x8*)(p + 512) = o1; *(f16x8*)(p + 1024) = o2;
}

// ---- fused output projections: [0,576)=Wo0 (4096x2304,K=2048),
//      [576,704)=Wo1 (2048x1024,K=2048) ------------------------------------
__global__ __launch_bounds__(256) void k_oproj(
    const f16* __restrict__ att0, const f16* __restrict__ att1,
    const f16* __restrict__ wo0,  const f16* __restrict__ wo1,
    float* __restrict__ out0, float* __restrict__ out1)
{
  __shared__ alignas(16) f16 At[128 * 32];
  __shared__ alignas(16) f16 Bt[128 * 32];
  const int idx = blockIdx.x;
  int by, bx, ldc;
  const f16 *A, *B;
  float* C;
  if (idx < 576) { by = idx / 18; bx = idx % 18;
                   A = att0 + (size_t)by * 128 * 2048; B = wo0 + (size_t)bx * 128 * 2048;
                   C = out0; ldc = 2304; }
  else           { int j = idx - 576; by = j >> 3; bx = j & 7;
                   A = att1 + (size_t)by * 128 * 2048; B = wo1 + (size_t)bx * 128 * 2048;
                   C = out1; ldc = 1024; }
  const int rowbase = by * 128, colbase = bx * 128;
  gemm_core(At, Bt, A, 2048, B, 2048, 2048, [&](int r, int c, float fv) {
    C[(size_t)(rowbase + r) * ldc + colbase + c] = fv;
  });
}

// ---- cast all fp32 inputs to f16, contiguous into ws -----------------------
__global__ __launch_bounds__(256) void k_cast_all(
    const float* __restrict__ s0, const float* __restrict__ s1,
    const float* __restrict__ s2, const float* __restrict__ s3,
    const float* __restrict__ s4, const float* __restrict__ s5,
    const float* __restrict__ s6, const float* __restrict__ s7,
    const float* __restrict__ s8, const float* __restrict__ s9,
    f16* __restrict__ dst)
{
  const size_t gid = ((size_t)blockIdx.x * 256 + threadIdx.x) * 4;
  const float* s; size_t off;
  if      (gid < 9437184ull)  { s = s0; off = gid;               }
  else if (gid < 11534336ull) { s = s1; off = gid - 9437184ull;  }
  else if (gid < 16252928ull) { s = s2; off = gid - 11534336ull; }
  else if (gid < 18612224ull) { s = s3; off = gid - 16252928ull; }
  else if (gid < 20971520ull) { s = s4; off = gid - 18612224ull; }
  else if (gid < 25690112ull) { s = s5; off = gid - 20971520ull; }
  else if (gid < 27787264ull) { s = s6; off = gid - 25690112ull; }
  else if (gid < 28835840ull) { s = s7; off = gid - 27787264ull; }
  else if (gid < 29884416ull) { s = s8; off = gid - 28835840ull; }
  else                        { s = s9; off = gid - 29884416ull; }
  float4 v = *(const float4*)(s + off);
  f16x4 o = {(f16)v.x, (f16)v.y, (f16)v.z, (f16)v.w};
  *(f16x4*)(dst + gid) = o;
}

// ---------------------------------------------------------------------------
extern "C" void kernel_launch(void* const* d_in, const int* in_sizes, int n_in,
                              void* d_out, int out_size, void* d_ws, size_t ws_size,
                              hipStream_t stream)
{
  (void)in_sizes; (void)n_in; (void)out_size; (void)ws_size;
  const float* pg  = (const float*)d_in[0];
  const float* ex  = (const float*)d_in[1];
  const float* cs  = (const float*)d_in[2];
  const float* sn  = (const float*)d_in[3];
  const float* msk = (const float*)d_in[4];

  char* ws = (char*)d_ws;
  // cast region (contiguous, k_cast_all order):
  f16* xpg  = (f16*)(ws + 0);           // [4096,2304]   (dead after qkv)
  f16* xex  = (f16*)(ws + 18874368);    // [2048,1024]   (dead after qkv)
  f16* W0c  = (f16*)(ws + 23068672);    // [4096,2304] = Wq0;Wk0;Wv0 (dead)
  f16* wo0c = (f16*)(ws + 41943040);    // [2304,2048]
  f16* W1c  = (f16*)(ws + 51380224);    // [4096,1024] = Wq1;Wk1;Wv1 (dead)
  f16* wo1c = (f16*)(ws + 59768832);    // [1024,2048]
  f16* qb   = (f16*)(ws + 63963136);    // [B*1536, 2048] f16 (roped in place)
  f16* kb   = (f16*)(ws + 89128960);    // [B*1536, 1024]
  f16* vb   = (f16*)(ws + 101711872);   // [B*1536, 1024] (dead after vtrans)
  f16* vt   = (f16*)(ws + 114294784);   // [B,4,256,1536]
  f16* att0 = (f16*)(ws + 126877696);   // [B*1024, 2048]
  f16* att1 = (f16*)(ws + 143654912);   // [B*512, 2048]
  f16* S0   = (f16*)(ws + 152043520);   // f16 S/P chunk A: 8*1536*1536
  f16* S1   = (f16*)(ws + 189792256);   // f16 S/P chunk B (ends 227,540,992)
  float* out0 = (float*)d_out;          // [4,1024,2304]
  float* out1 = out0 + 9437184;         // [4,512,1024]

  // 1) cast all fp32 inputs to f16
  k_cast_all<<<31232, 256, 0, stream>>>(
      pg, ex,
      (const float*)d_in[5], (const float*)d_in[6], (const float*)d_in[7],
      (const float*)d_in[8], (const float*)d_in[9], (const float*)d_in[10],
      (const float*)d_in[11], (const float*)d_in[12], (f16*)ws);

  // 2) fused QKV (both streams, 1536 blocks)
  k_qkv<<<1536, 256, 0, stream>>>(xpg, xex, W0c, W1c, qb, kb, vb);

  // 3) in-place RoPE (q + k in one launch)
  k_rope2<<<36864, 256, 0, stream>>>(qb, kb, cs, sn);

  // 4) V transpose
  k_vtrans<<<dim3(32, 48, 4), 256, 0, stream>>>(vb, vt);

  // 5) attention pipeline: scores_b / softmax_b / pv_b with pv fused into the
  //    next batch's scores launch (double-buffered f16 S chunks)
  k_attn<<<1152, 256, 0, stream>>>(qb, kb, msk, S0, S0, vt, att0, att1, 0, 0, 0);
  k_softmax<<<3072, 256, 0, stream>>>(S0);
  k_attn<<<1344, 256, 0, stream>>>(qb, kb, msk, S1, S0, vt, att0, att1, 1, 0, 192);
  k_softmax<<<3072, 256, 0, stream>>>(S1);
  k_attn<<<1344, 256, 0, stream>>>(qb, kb, msk, S0, S1, vt, att0, att1, 2, 1, 192);
  k_softmax<<<3072, 256, 0, stream>>>(S0);
  k_attn<<<1344, 256, 0, stream>>>(qb, kb, msk, S1, S0, vt, att0, att1, 3, 2, 192);
  k_softmax<<<3072, 256, 0, stream>>>(S1);
  k_attn<<<192, 256, 0, stream>>>(qb, kb, msk, S0, S1, vt, att0, att1, 0, 3, 192);

  // 6) fused output projections (704 blocks)
  k_oproj<<<704, 256, 0, stream>>>(att0, att1, wo0c, wo1c, out0, out1);
}